// Round 10
// baseline (306.879 us; speedup 1.0000x reference)
//
#include <hip/hip_runtime.h>
#include <hip/hip_bf16.h>

// Edges GNN message MLP: per-edge RBF(100) + gather h[src],h[dst] (64+64)
// -> Linear(228->128) -> SiLU -> Linear(128->64).
// R12 design = R11 (operand-swapped 32x32x16, zero-shuffle hand-off) + 3 fixes:
// 1) Register peak: epilogue converts ALL acc1 -> P[32] packed-bf16 u32 regs
//    BEFORE acc2 exists (peak ~160 -> ~105 regs -> 4 waves/SIMD, was 3.2).
// 2) Store amplification (R11: WRITE 262MB vs 200MB output): W2 ROW perm pi
//    (r=8g+4h+i -> 16h+4g+i) in pack_w makes each lane's acc2 16 CONTIGUOUS
//    output floats -> 2x64B full-sector runs per lane, no RFO.
// 3) VALU/trans: RBF via geometric recurrence (v*=r, r*=exp(-0.2); exact on
//    the uniform 0.1 grid) = 2 exps + 14 muls per 8 values instead of 8 exps;
//    bf16 packing via bf16x2 vector casts (cvt_pk) instead of shift/or.
// LDS = 60K (B1) + 16K (B2) = 76 KB -> 2 blocks/CU @ 512 thr, one barrier.

#define FEAT      64
#define NMU       100
#define K1_REAL   228
#define WEDGES    32        // edges per wave (one 32-row m-tile)
#define NWAVES    8
#define BEDGES    (WEDGES * NWAVES)   // 256 edges per block
#define HN8       400000    // (50000*64)/8 bf16x8 groups in h
#define B1N_ELEMS 30720     // 30 (ksh) * 128 (n) * 8 (j) bf16 = 60 KB
#define B2N_ELEMS 8192      // 16 (sh) * 64 (slot) * 8 (j) bf16 = 16 KB
#define RBF_C     0.81873075f   // exp(-0.2)

typedef __bf16  bf16x8 __attribute__((ext_vector_type(8)));
typedef __bf16  bf16x2 __attribute__((ext_vector_type(2)));
typedef float   fx16   __attribute__((ext_vector_type(16)));

// Pack W1 [128 x 228] -> B1[(ksh*128 + n)*8 + j] = W1[n][8*ksh + j]
// (ksh = ks*2 + h5, ks = 0..14; zero for k >= 228). 32x32x16 A-frag order:
// lane l reads row n = tile*32 + (l&31), k = 8*(l>>5) + j contiguous 16B.
// Pack W2 [64 x 128] -> B2[(sh*64 + n2t*32 + r)*8 + j] =
//   W2[n2t*32 + pi(r)][rho(sh,j)]
// rho = k-slot -> H-row perm making layer2's B-fragment lane-local (R11);
// pi(r) = 16*((r>>2)&1) + 4*(r>>3) + (r&3): D-row r holds output feature
// pi(r), so lane (m,h5) owns features n2t*32 + 16*h5 + (0..15) contiguous.
__global__ void pack_w(const float* __restrict__ W1, const float* __restrict__ W2,
                       __bf16* __restrict__ B1, __bf16* __restrict__ B2) {
    int i = blockIdx.x * 256 + threadIdx.x;     // 0..38911
    if (i < B1N_ELEMS) {
        int j   = i & 7;
        int n   = (i >> 3) & 127;
        int ksh = i >> 10;                      // 0..29
        int k   = ksh * 8 + j;                  // 0..239
        float v = (k < K1_REAL) ? W1[n * K1_REAL + k] : 0.0f;
        B1[i] = (__bf16)v;
    } else if (i < B1N_ELEMS + B2N_ELEMS) {
        int t    = i - B1N_ELEMS;
        int j    = t & 7;
        int slot = (t >> 3) & 63;               // n2t*32 + r
        int sh   = t >> 9;                      // 0..15
        int r    = slot & 31;
        int n2t  = slot >> 5;
        int f    = (((r >> 2) & 1) << 4) | ((r >> 3) << 2) | (r & 3);
        int rho  = ((sh >> 2) << 5) | (((sh >> 1) & 1) << 4)
                 | ((j >> 2) << 3) | ((sh & 1) << 2) | (j & 3);
        B2[t] = (__bf16)W2[(n2t * 32 + f) * 128 + rho];
    }
}

// Convert h [50000 x 64] fp32 -> bf16 table (row-major, same layout).
__global__ void pack_h(const float* __restrict__ h, __bf16* __restrict__ hb) {
    int i = blockIdx.x * 256 + threadIdx.x;     // one bf16x8 group each
    if (i >= HN8) return;
    const float4* p = (const float4*)h + (size_t)i * 2;
    float4 v0 = p[0];
    float4 v1 = p[1];
    bf16x8 b = { (__bf16)v0.x, (__bf16)v0.y, (__bf16)v0.z, (__bf16)v0.w,
                 (__bf16)v1.x, (__bf16)v1.y, (__bf16)v1.z, (__bf16)v1.w };
    ((bf16x8*)hb)[i] = b;
}

__device__ __forceinline__ bf16x8 hfrag_f32(const float* __restrict__ h, int node, int cb) {
    const float4* p = (const float4*)(h + (size_t)node * FEAT + cb);
    float4 v0 = p[0];
    float4 v1 = p[1];
    bf16x8 a = { (__bf16)v0.x, (__bf16)v0.y, (__bf16)v0.z, (__bf16)v0.w,
                 (__bf16)v1.x, (__bf16)v1.y, (__bf16)v1.z, (__bf16)v1.w };
    return a;
}

__device__ __forceinline__ float silu(float z) {
    // v_rcp_f32 (~1 ulp) -- error far below bf16 storage rounding.
    return z * __builtin_amdgcn_rcpf(1.0f + __expf(-z));
}

template<bool HB16>
__global__ __launch_bounds__(512, 4)
void edges_fused(const float* __restrict__ h,
                 const __bf16* __restrict__ hb,
                 const int*   __restrict__ src,
                 const int*   __restrict__ dst,
                 const float* __restrict__ enorm,
                 const float* __restrict__ mu,
                 const __bf16* __restrict__ B1,
                 const __bf16* __restrict__ B2,
                 float* __restrict__ out,
                 int E) {
    // 60K + 16K = 76 KB static LDS -> 2 blocks/CU.
    __shared__ __align__(16) __bf16 B1s[B1N_ELEMS];
    __shared__ __align__(16) __bf16 B2s[B2N_ELEMS];

    const int tid = threadIdx.x;
    const int w   = tid >> 6;
    const int m   = tid & 31;          // edge within the wave's 32-row tile
    const int h5  = (tid >> 5) & 1;    // lane>>5: k-half selector
    const int g0  = blockIdx.x * BEDGES + w * WEDGES;
    const bool act = (g0 < E);

    // ---- Edge data + SRC gathers (before the staging barrier) ----
    int ndst;
    float dval;
    bf16x8 ags[4];                     // 16 VGPRs: k-chunks 16*ks+8*h5 .. +7
    if (act) {
        int e = g0 + m;
        int nsrc = src[e];
        ndst = dst[e];
        dval = enorm[e];
#pragma unroll
        for (int ks = 0; ks < 4; ++ks) {
            const int cb = ks * 16 + h5 * 8;
            if constexpr (HB16)
                ags[ks] = *(const bf16x8*)(hb + (size_t)nsrc * FEAT + cb);
            else
                ags[ks] = hfrag_f32(h, nsrc, cb);
        }
    }

    // ---- Stage weights into LDS (once per block) ----
    {
        const bf16x8* gB1 = (const bf16x8*)B1;
        const bf16x8* gB2 = (const bf16x8*)B2;
        bf16x8* sB1 = (bf16x8*)B1s;
        bf16x8* sB2 = (bf16x8*)B2s;
#pragma unroll
        for (int it = 0; it < 8; ++it) {         // 3840 groups / 512 thr
            int g = it * 512 + tid;
            if (g < B1N_ELEMS / 8) sB1[g] = gB1[g];
        }
#pragma unroll
        for (int it = 0; it < 2; ++it) {         // 1024 groups / 512 thr
            int g = it * 512 + tid;
            sB2[g] = gB2[g];
        }
    }
    __syncthreads();
    if (!act) return;                            // after the only barrier

    // ---- Layer 1: H^T[128 x 32] = W1[128 x 240] . X^T[240 x 32] ----
    // acc1[nt1]: D rows = hidden n (nt1*32 + 8g + 4*h5 + i), col = edge m.
    fx16 acc1[4] = {};

    // RBF k-steps first (VALU+MFMA) -- slack for in-flight src gathers.
    // Geometric recurrence: v_{k+1} = v_k * r, r *= exp(-0.2). Exact for the
    // uniform 0.1 grid; a window (0.7 wide) cannot span from flushed-zero
    // (|t|>3.2) to significant (|t|<1), so underflow-propagation is harmless.
#pragma unroll
    for (int ks = 8; ks < 14; ++ks) {
        const int c0 = ks * 16 - 128 + h5 * 8;   // RBF col base, < 96
        const float t0 = mu[c0] - dval;
        float v = __expf(-10.f * t0 * t0);
        float rr = __expf(-2.f * t0 - 0.1f);
        float e0 = v, e1, e2, e3, e4, e5, e6, e7;
        v *= rr; rr *= RBF_C; e1 = v;
        v *= rr; rr *= RBF_C; e2 = v;
        v *= rr; rr *= RBF_C; e3 = v;
        v *= rr; rr *= RBF_C; e4 = v;
        v *= rr; rr *= RBF_C; e5 = v;
        v *= rr; rr *= RBF_C; e6 = v;
        v *= rr;              e7 = v;
        bf16x8 a = { (__bf16)e0, (__bf16)e1, (__bf16)e2, (__bf16)e3,
                     (__bf16)e4, (__bf16)e5, (__bf16)e6, (__bf16)e7 };
        const int base = ((ks * 2 + h5) * 128 + m) * 8;
#pragma unroll
        for (int nt1 = 0; nt1 < 4; ++nt1) {
            bf16x8 a1 = *(const bf16x8*)&B1s[base + nt1 * 256];
            acc1[nt1] = __builtin_amdgcn_mfma_f32_32x32x16_bf16(a1, a, acc1[nt1], 0, 0, 0);
        }
    }
    // ks = 14: cols 224..239; real only k < 228 -> h5==0, j<4 (direct).
    {
        float4 m7 = *(const float4*)(mu + 96);
        const float d = dval;
        const bool lo = (h5 == 0);
        const __bf16 zz = (__bf16)0.0f;
        float t0 = m7.x - d, t1 = m7.y - d, t2 = m7.z - d, t3 = m7.w - d;
        bf16x8 a = { lo ? (__bf16)__expf(-10.f * t0 * t0) : zz,
                     lo ? (__bf16)__expf(-10.f * t1 * t1) : zz,
                     lo ? (__bf16)__expf(-10.f * t2 * t2) : zz,
                     lo ? (__bf16)__expf(-10.f * t3 * t3) : zz,
                     zz, zz, zz, zz };
        const int base = ((14 * 2 + h5) * 128 + m) * 8;
#pragma unroll
        for (int nt1 = 0; nt1 < 4; ++nt1) {
            bf16x8 a1 = *(const bf16x8*)&B1s[base + nt1 * 256];
            acc1[nt1] = __builtin_amdgcn_mfma_f32_32x32x16_bf16(a1, a, acc1[nt1], 0, 0, 0);
        }
    }
    // ks = 0..3: src features (in registers since before staging)
#pragma unroll
    for (int ks = 0; ks < 4; ++ks) {
        const int base = ((ks * 2 + h5) * 128 + m) * 8;
#pragma unroll
        for (int nt1 = 0; nt1 < 4; ++nt1) {
            bf16x8 a1 = *(const bf16x8*)&B1s[base + nt1 * 256];
            acc1[nt1] = __builtin_amdgcn_mfma_f32_32x32x16_bf16(a1, ags[ks], acc1[nt1], 0, 0, 0);
        }
    }
    // dst gathers into the SAME registers (ags dead after ks=3 consume)
#pragma unroll
    for (int ks = 0; ks < 4; ++ks) {
        const int cb = ks * 16 + h5 * 8;
        if constexpr (HB16)
            ags[ks] = *(const bf16x8*)(hb + (size_t)ndst * FEAT + cb);
        else
            ags[ks] = hfrag_f32(h, ndst, cb);
    }
    // ks = 4..7: dst features
#pragma unroll
    for (int ks = 4; ks < 8; ++ks) {
        const int base = ((ks * 2 + h5) * 128 + m) * 8;
#pragma unroll
        for (int nt1 = 0; nt1 < 4; ++nt1) {
            bf16x8 a1 = *(const bf16x8*)&B1s[base + nt1 * 256];
            acc1[nt1] = __builtin_amdgcn_mfma_f32_32x32x16_bf16(a1, ags[ks - 4], acc1[nt1], 0, 0, 0);
        }
    }

    // ---- Epilogue phase 1: SiLU + pack ALL of acc1 into P[32] (u32 of
    // 2xbf16). acc1 dies here, BEFORE acc2 is created -> register peak drops
    // from 160 (R11: 3.2 waves/SIMD) to ~105 (target 4 waves/SIMD).
    // P[s*4 + i] is exactly layer2 k-step s's B-fragment word i.
    uint32_t P[32];
#pragma unroll
    for (int nt1 = 0; nt1 < 4; ++nt1) {
#pragma unroll
        for (int gp = 0; gp < 8; ++gp) {
            union { bf16x2 v; uint32_t u; } cv;
            cv.v = (bf16x2){ (__bf16)silu(acc1[nt1][2 * gp]),
                             (__bf16)silu(acc1[nt1][2 * gp + 1]) };
            P[nt1 * 8 + gp] = cv.u;
        }
    }

    // ---- Epilogue phase 2: O^T[64 x 32] = W2[64 x 128] . H^T[128 x 32].
    fx16 acc2[2] = {};
#pragma unroll
    for (int s = 0; s < 8; ++s) {
        union { uint32_t u[4]; bf16x8 v; } uu;
        uu.u[0] = P[4 * s + 0]; uu.u[1] = P[4 * s + 1];
        uu.u[2] = P[4 * s + 2]; uu.u[3] = P[4 * s + 3];
        const int base2 = ((s * 2 + h5) * 64 + m) * 8;
#pragma unroll
        for (int n2t = 0; n2t < 2; ++n2t) {
            bf16x8 a2 = *(const bf16x8*)&B2s[base2 + n2t * 256];
            acc2[n2t] = __builtin_amdgcn_mfma_f32_32x32x16_bf16(a2, uu.v, acc2[n2t], 0, 0, 0);
        }
    }

    // ---- Store: pi made lane features contiguous: lane (m,h5) owns output
    // features n2t*32 + h5*16 + reg (reg 0..15) -> 2x 64B contiguous runs.
    float* orow = out + (size_t)(g0 + m) * 64 + h5 * 16;
#pragma unroll
    for (int n2t = 0; n2t < 2; ++n2t)
#pragma unroll
        for (int qd = 0; qd < 4; ++qd) {
            float4 st = { acc2[n2t][4 * qd + 0], acc2[n2t][4 * qd + 1],
                          acc2[n2t][4 * qd + 2], acc2[n2t][4 * qd + 3] };
            *(float4*)(orow + n2t * 32 + qd * 4) = st;
        }
}

extern "C" void kernel_launch(void* const* d_in, const int* in_sizes, int n_in,
                              void* d_out, int out_size, void* d_ws, size_t ws_size,
                              hipStream_t stream) {
    const float* h   = (const float*)d_in[0];
    const int*   src = (const int*)d_in[1];
    const int*   dst = (const int*)d_in[2];
    const float* en  = (const float*)d_in[3];
    const float* mu  = (const float*)d_in[4];
    const float* W1  = (const float*)d_in[5];
    const float* W2  = (const float*)d_in[6];

    __bf16* B1 = (__bf16*)d_ws;                            // 61440 B
    __bf16* B2 = (__bf16*)((char*)d_ws + 61440);           // 16384 B
    __bf16* HB = (__bf16*)((char*)d_ws + 77824);           // 6.4 MB

    const size_t ws_needed = 77824 + (size_t)HN8 * 8 * sizeof(__bf16);
    const bool   use_hb    = ws_size >= ws_needed;

    pack_w<<<(B1N_ELEMS + B2N_ELEMS) / 256, 256, 0, stream>>>(W1, W2, B1, B2);

    const int E = in_sizes[1];                 // 800000
    const int nblocks = (E + BEDGES - 1) / BEDGES;   // 3125

    if (use_hb) {
        pack_h<<<(HN8 + 255) / 256, 256, 0, stream>>>(h, HB);
        edges_fused<true><<<nblocks, 512, 0, stream>>>(h, HB, src, dst, en, mu, B1, B2, (float*)d_out, E);
    } else {
        edges_fused<false><<<nblocks, 512, 0, stream>>>(h, nullptr, src, dst, en, mu, B1, B2, (float*)d_out, E);
    }
}

// Round 11
// 298.366 us; speedup vs baseline: 1.0285x; 1.0285x over previous
//
#include <hip/hip_runtime.h>
#include <hip/hip_bf16.h>

// Edges GNN message MLP: per-edge RBF(100) + gather h[src],h[dst] (64+64)
// -> Linear(228->128) -> SiLU -> Linear(128->64).
// R13 = R12 (operand-swapped 32x32x16, zero-shuffle hand-off, clean stores,
// RBF recurrence) + FORCED 4 waves/SIMD via amdgpu_waves_per_eu(4).
// Evidence: R9/R11/R12 (three different structures) all land at 127-129us
// with OccupancyPercent ~35% == 3 waves/SIMD == ~160-reg allocation; every
// pipe cut (VALU -10pts, DS conflicts ->0, -60MB stores) moved nothing.
// Liveness says <=120 regs suffices (acc1 dies before acc2 is created), so
// the cap should be spill-free; WRITE_SIZE == 200000 KB is the tripwire.
// LDS = 60K (B1) + 16K (B2) = 76 KB -> 2 blocks/CU @ 512 thr, one barrier.

#define FEAT      64
#define NMU       100
#define K1_REAL   228
#define WEDGES    32        // edges per wave (one 32-row m-tile)
#define NWAVES    8
#define BEDGES    (WEDGES * NWAVES)   // 256 edges per block
#define HN8       400000    // (50000*64)/8 bf16x8 groups in h
#define B1N_ELEMS 30720     // 30 (ksh) * 128 (n) * 8 (j) bf16 = 60 KB
#define B2N_ELEMS 8192      // 16 (sh) * 64 (slot) * 8 (j) bf16 = 16 KB
#define RBF_C     0.81873075f   // exp(-0.2)

typedef __bf16  bf16x8 __attribute__((ext_vector_type(8)));
typedef __bf16  bf16x2 __attribute__((ext_vector_type(2)));
typedef float   fx16   __attribute__((ext_vector_type(16)));

// Pack W1 [128 x 228] -> B1[(ksh*128 + n)*8 + j] = W1[n][8*ksh + j]
// (ksh = ks*2 + h5, ks = 0..14; zero for k >= 228). 32x32x16 A-frag order:
// lane l reads row n = tile*32 + (l&31), k = 8*(l>>5) + j contiguous 16B.
// Pack W2 [64 x 128] -> B2[(sh*64 + n2t*32 + r)*8 + j] =
//   W2[n2t*32 + pi(r)][rho(sh,j)]
// rho = k-slot -> H-row perm making layer2's B-fragment lane-local;
// pi(r) = 16*((r>>2)&1) + 4*(r>>3) + (r&3): D-row r holds output feature
// pi(r), so lane (m,h5) owns features n2t*32 + 16*h5 + (0..15) contiguous.
__global__ void pack_w(const float* __restrict__ W1, const float* __restrict__ W2,
                       __bf16* __restrict__ B1, __bf16* __restrict__ B2) {
    int i = blockIdx.x * 256 + threadIdx.x;     // 0..38911
    if (i < B1N_ELEMS) {
        int j   = i & 7;
        int n   = (i >> 3) & 127;
        int ksh = i >> 10;                      // 0..29
        int k   = ksh * 8 + j;                  // 0..239
        float v = (k < K1_REAL) ? W1[n * K1_REAL + k] : 0.0f;
        B1[i] = (__bf16)v;
    } else if (i < B1N_ELEMS + B2N_ELEMS) {
        int t    = i - B1N_ELEMS;
        int j    = t & 7;
        int slot = (t >> 3) & 63;               // n2t*32 + r
        int sh   = t >> 9;                      // 0..15
        int r    = slot & 31;
        int n2t  = slot >> 5;
        int f    = (((r >> 2) & 1) << 4) | ((r >> 3) << 2) | (r & 3);
        int rho  = ((sh >> 2) << 5) | (((sh >> 1) & 1) << 4)
                 | ((j >> 2) << 3) | ((sh & 1) << 2) | (j & 3);
        B2[t] = (__bf16)W2[(n2t * 32 + f) * 128 + rho];
    }
}

// Convert h [50000 x 64] fp32 -> bf16 table (row-major, same layout).
__global__ void pack_h(const float* __restrict__ h, __bf16* __restrict__ hb) {
    int i = blockIdx.x * 256 + threadIdx.x;     // one bf16x8 group each
    if (i >= HN8) return;
    const float4* p = (const float4*)h + (size_t)i * 2;
    float4 v0 = p[0];
    float4 v1 = p[1];
    bf16x8 b = { (__bf16)v0.x, (__bf16)v0.y, (__bf16)v0.z, (__bf16)v0.w,
                 (__bf16)v1.x, (__bf16)v1.y, (__bf16)v1.z, (__bf16)v1.w };
    ((bf16x8*)hb)[i] = b;
}

__device__ __forceinline__ bf16x8 hfrag_f32(const float* __restrict__ h, int node, int cb) {
    const float4* p = (const float4*)(h + (size_t)node * FEAT + cb);
    float4 v0 = p[0];
    float4 v1 = p[1];
    bf16x8 a = { (__bf16)v0.x, (__bf16)v0.y, (__bf16)v0.z, (__bf16)v0.w,
                 (__bf16)v1.x, (__bf16)v1.y, (__bf16)v1.z, (__bf16)v1.w };
    return a;
}

__device__ __forceinline__ float silu(float z) {
    // v_rcp_f32 (~1 ulp) -- error far below bf16 storage rounding.
    return z * __builtin_amdgcn_rcpf(1.0f + __expf(-z));
}

template<bool HB16>
__global__
__attribute__((amdgpu_flat_work_group_size(512, 512), amdgpu_waves_per_eu(4)))
void edges_fused(const float* __restrict__ h,
                 const __bf16* __restrict__ hb,
                 const int*   __restrict__ src,
                 const int*   __restrict__ dst,
                 const float* __restrict__ enorm,
                 const float* __restrict__ mu,
                 const __bf16* __restrict__ B1,
                 const __bf16* __restrict__ B2,
                 float* __restrict__ out,
                 int E) {
    // 60K + 16K = 76 KB static LDS -> 2 blocks/CU.
    __shared__ __align__(16) __bf16 B1s[B1N_ELEMS];
    __shared__ __align__(16) __bf16 B2s[B2N_ELEMS];

    const int tid = threadIdx.x;
    const int w   = tid >> 6;
    const int m   = tid & 31;          // edge within the wave's 32-row tile
    const int h5  = (tid >> 5) & 1;    // lane>>5: k-half selector
    const int g0  = blockIdx.x * BEDGES + w * WEDGES;
    const bool act = (g0 < E);

    // ---- Edge data + SRC gathers (before the staging barrier) ----
    int ndst;
    float dval;
    bf16x8 ags[4];                     // 16 VGPRs: k-chunks 16*ks+8*h5 .. +7
    if (act) {
        int e = g0 + m;
        int nsrc = src[e];
        ndst = dst[e];
        dval = enorm[e];
#pragma unroll
        for (int ks = 0; ks < 4; ++ks) {
            const int cb = ks * 16 + h5 * 8;
            if constexpr (HB16)
                ags[ks] = *(const bf16x8*)(hb + (size_t)nsrc * FEAT + cb);
            else
                ags[ks] = hfrag_f32(h, nsrc, cb);
        }
    }

    // ---- Stage weights into LDS (once per block) ----
    {
        const bf16x8* gB1 = (const bf16x8*)B1;
        const bf16x8* gB2 = (const bf16x8*)B2;
        bf16x8* sB1 = (bf16x8*)B1s;
        bf16x8* sB2 = (bf16x8*)B2s;
#pragma unroll
        for (int it = 0; it < 8; ++it) {         // 3840 groups / 512 thr
            int g = it * 512 + tid;
            if (g < B1N_ELEMS / 8) sB1[g] = gB1[g];
        }
#pragma unroll
        for (int it = 0; it < 2; ++it) {         // 1024 groups / 512 thr
            int g = it * 512 + tid;
            sB2[g] = gB2[g];
        }
    }
    __syncthreads();
    if (!act) return;                            // after the only barrier

    // ---- Layer 1: H^T[128 x 32] = W1[128 x 240] . X^T[240 x 32] ----
    // acc1[nt1]: D rows = hidden n (nt1*32 + 8g + 4*h5 + i), col = edge m.
    fx16 acc1[4] = {};

    // RBF k-steps first (VALU+MFMA) -- slack for in-flight src gathers.
    // Geometric recurrence: v_{k+1} = v_k * r, r *= exp(-0.2). Exact for the
    // uniform 0.1 grid; a window (0.7 wide) cannot span from flushed-zero
    // (|t|>3.2) to significant (|t|<1), so underflow-propagation is harmless.
#pragma unroll
    for (int ks = 8; ks < 14; ++ks) {
        const int c0 = ks * 16 - 128 + h5 * 8;   // RBF col base, < 96
        const float t0 = mu[c0] - dval;
        float v = __expf(-10.f * t0 * t0);
        float rr = __expf(-2.f * t0 - 0.1f);
        float e0 = v, e1, e2, e3, e4, e5, e6, e7;
        v *= rr; rr *= RBF_C; e1 = v;
        v *= rr; rr *= RBF_C; e2 = v;
        v *= rr; rr *= RBF_C; e3 = v;
        v *= rr; rr *= RBF_C; e4 = v;
        v *= rr; rr *= RBF_C; e5 = v;
        v *= rr; rr *= RBF_C; e6 = v;
        v *= rr;              e7 = v;
        bf16x8 a = { (__bf16)e0, (__bf16)e1, (__bf16)e2, (__bf16)e3,
                     (__bf16)e4, (__bf16)e5, (__bf16)e6, (__bf16)e7 };
        const int base = ((ks * 2 + h5) * 128 + m) * 8;
#pragma unroll
        for (int nt1 = 0; nt1 < 4; ++nt1) {
            bf16x8 a1 = *(const bf16x8*)&B1s[base + nt1 * 256];
            acc1[nt1] = __builtin_amdgcn_mfma_f32_32x32x16_bf16(a1, a, acc1[nt1], 0, 0, 0);
        }
    }
    // ks = 14: cols 224..239; real only k < 228 -> h5==0, j<4 (direct).
    {
        float4 m7 = *(const float4*)(mu + 96);
        const float d = dval;
        const bool lo = (h5 == 0);
        const __bf16 zz = (__bf16)0.0f;
        float t0 = m7.x - d, t1 = m7.y - d, t2 = m7.z - d, t3 = m7.w - d;
        bf16x8 a = { lo ? (__bf16)__expf(-10.f * t0 * t0) : zz,
                     lo ? (__bf16)__expf(-10.f * t1 * t1) : zz,
                     lo ? (__bf16)__expf(-10.f * t2 * t2) : zz,
                     lo ? (__bf16)__expf(-10.f * t3 * t3) : zz,
                     zz, zz, zz, zz };
        const int base = ((14 * 2 + h5) * 128 + m) * 8;
#pragma unroll
        for (int nt1 = 0; nt1 < 4; ++nt1) {
            bf16x8 a1 = *(const bf16x8*)&B1s[base + nt1 * 256];
            acc1[nt1] = __builtin_amdgcn_mfma_f32_32x32x16_bf16(a1, a, acc1[nt1], 0, 0, 0);
        }
    }
    // ks = 0..3: src features (in registers since before staging)
#pragma unroll
    for (int ks = 0; ks < 4; ++ks) {
        const int base = ((ks * 2 + h5) * 128 + m) * 8;
#pragma unroll
        for (int nt1 = 0; nt1 < 4; ++nt1) {
            bf16x8 a1 = *(const bf16x8*)&B1s[base + nt1 * 256];
            acc1[nt1] = __builtin_amdgcn_mfma_f32_32x32x16_bf16(a1, ags[ks], acc1[nt1], 0, 0, 0);
        }
    }
    // dst gathers into the SAME registers (ags dead after ks=3 consume)
#pragma unroll
    for (int ks = 0; ks < 4; ++ks) {
        const int cb = ks * 16 + h5 * 8;
        if constexpr (HB16)
            ags[ks] = *(const bf16x8*)(hb + (size_t)ndst * FEAT + cb);
        else
            ags[ks] = hfrag_f32(h, ndst, cb);
    }
    // ks = 4..7: dst features
#pragma unroll
    for (int ks = 4; ks < 8; ++ks) {
        const int base = ((ks * 2 + h5) * 128 + m) * 8;
#pragma unroll
        for (int nt1 = 0; nt1 < 4; ++nt1) {
            bf16x8 a1 = *(const bf16x8*)&B1s[base + nt1 * 256];
            acc1[nt1] = __builtin_amdgcn_mfma_f32_32x32x16_bf16(a1, ags[ks - 4], acc1[nt1], 0, 0, 0);
        }
    }

    // ---- Epilogue phase 1: SiLU + pack ALL of acc1 into P[32] (u32 of
    // 2xbf16). acc1 dies here, BEFORE acc2 is created -> the <=128-reg
    // allocation the waves_per_eu(4) cap requires exists.
    // P[s*4 + i] is exactly layer2 k-step s's B-fragment word i.
    uint32_t P[32];
#pragma unroll
    for (int nt1 = 0; nt1 < 4; ++nt1) {
#pragma unroll
        for (int gp = 0; gp < 8; ++gp) {
            union { bf16x2 v; uint32_t u; } cv;
            cv.v = (bf16x2){ (__bf16)silu(acc1[nt1][2 * gp]),
                             (__bf16)silu(acc1[nt1][2 * gp + 1]) };
            P[nt1 * 8 + gp] = cv.u;
        }
    }

    // ---- Epilogue phase 2: O^T[64 x 32] = W2[64 x 128] . H^T[128 x 32].
    fx16 acc2[2] = {};
#pragma unroll
    for (int s = 0; s < 8; ++s) {
        union { uint32_t u[4]; bf16x8 v; } uu;
        uu.u[0] = P[4 * s + 0]; uu.u[1] = P[4 * s + 1];
        uu.u[2] = P[4 * s + 2]; uu.u[3] = P[4 * s + 3];
        const int base2 = ((s * 2 + h5) * 64 + m) * 8;
#pragma unroll
        for (int n2t = 0; n2t < 2; ++n2t) {
            bf16x8 a2 = *(const bf16x8*)&B2s[base2 + n2t * 256];
            acc2[n2t] = __builtin_amdgcn_mfma_f32_32x32x16_bf16(a2, uu.v, acc2[n2t], 0, 0, 0);
        }
    }

    // ---- Store: pi made lane features contiguous: lane (m,h5) owns output
    // features n2t*32 + h5*16 + reg (reg 0..15) -> 2x 64B contiguous runs.
    float* orow = out + (size_t)(g0 + m) * 64 + h5 * 16;
#pragma unroll
    for (int n2t = 0; n2t < 2; ++n2t)
#pragma unroll
        for (int qd = 0; qd < 4; ++qd) {
            float4 st = { acc2[n2t][4 * qd + 0], acc2[n2t][4 * qd + 1],
                          acc2[n2t][4 * qd + 2], acc2[n2t][4 * qd + 3] };
            *(float4*)(orow + n2t * 32 + qd * 4) = st;
        }
}

extern "C" void kernel_launch(void* const* d_in, const int* in_sizes, int n_in,
                              void* d_out, int out_size, void* d_ws, size_t ws_size,
                              hipStream_t stream) {
    const float* h   = (const float*)d_in[0];
    const int*   src = (const int*)d_in[1];
    const int*   dst = (const int*)d_in[2];
    const float* en  = (const float*)d_in[3];
    const float* mu  = (const float*)d_in[4];
    const float* W1  = (const float*)d_in[5];
    const float* W2  = (const float*)d_in[6];

    __bf16* B1 = (__bf16*)d_ws;                            // 61440 B
    __bf16* B2 = (__bf16*)((char*)d_ws + 61440);           // 16384 B
    __bf16* HB = (__bf16*)((char*)d_ws + 77824);           // 6.4 MB

    const size_t ws_needed = 77824 + (size_t)HN8 * 8 * sizeof(__bf16);
    const bool   use_hb    = ws_size >= ws_needed;

    pack_w<<<(B1N_ELEMS + B2N_ELEMS) / 256, 256, 0, stream>>>(W1, W2, B1, B2);

    const int E = in_sizes[1];                 // 800000
    const int nblocks = (E + BEDGES - 1) / BEDGES;   // 3125

    if (use_hb) {
        pack_h<<<(HN8 + 255) / 256, 256, 0, stream>>>(h, HB);
        edges_fused<true><<<nblocks, 512, 0, stream>>>(h, HB, src, dst, en, mu, B1, B2, (float*)d_out, E);
    } else {
        edges_fused<false><<<nblocks, 512, 0, stream>>>(h, nullptr, src, dst, en, mu, B1, B2, (float*)d_out, E);
    }
}